// Round 1
// baseline (580.153 us; speedup 1.0000x reference)
//
#include <hip/hip_runtime.h>
#include <hip/hip_bf16.h>
#include <stdint.h>

#define M_DIM 16384   // B*T = 4*4096
#define K_DIM 2048    // H
#define N_DIM 6144    // 3H

typedef __attribute__((ext_vector_type(8))) short bf16x8;
typedef __attribute__((ext_vector_type(8))) unsigned short u16x8;
typedef __attribute__((ext_vector_type(4))) float f32x4;

__device__ __forceinline__ unsigned short f2bf(float f) {
  unsigned int u = __float_as_uint(f);
  u += 0x7FFFu + ((u >> 16) & 1u);   // round-to-nearest-even
  return (unsigned short)(u >> 16);
}

__device__ __forceinline__ void load_lds16(const void* g, void* l) {
  __builtin_amdgcn_global_load_lds((const __attribute__((address_space(1))) void*)g,
                                   (__attribute__((address_space(3))) void*)l, 16, 0, 0);
}

// ---------- Pass 1a: hidden fp32 -> bf16 (straight copy) ----------
__global__ __launch_bounds__(256) void cvt_hidden(const float* __restrict__ in,
                                                  unsigned short* __restrict__ out) {
  unsigned int base = blockIdx.x * 256u + threadIdx.x;  // 2048 blocks * 256 = 524288 threads
  #pragma unroll
  for (int i = 0; i < 16; ++i) {
    unsigned int fi = i * 524288u + base;               // 8,388,608 float4s total
    float4 v = reinterpret_cast<const float4*>(in)[fi];
    ushort4 o;
    o.x = f2bf(v.x); o.y = f2bf(v.y); o.z = f2bf(v.z); o.w = f2bf(v.w);
    reinterpret_cast<ushort4*>(out)[fi] = o;
  }
}

// ---------- Pass 1b: w_qkv [K][N] fp32 -> Wt [N][K] bf16 (transpose+convert) ----------
__global__ __launch_bounds__(256) void cvt_w(const float* __restrict__ w,
                                             unsigned short* __restrict__ wt) {
  __shared__ float tile[64][69];   // pad 69 -> conflict-light column reads
  const int k0 = blockIdx.x * 64;  // 32 blocks
  const int n0 = blockIdx.y * 64;  // 96 blocks
  const int t = threadIdx.x;
  #pragma unroll
  for (int i = 0; i < 4; ++i) {
    int idx = i * 256 + t;
    int row = idx >> 4;      // 0..63 (k within tile)
    int c4  = idx & 15;      // float4 chunk within row
    float4 v = *reinterpret_cast<const float4*>(&w[(size_t)(k0 + row) * N_DIM + n0 + c4 * 4]);
    tile[row][c4 * 4 + 0] = v.x; tile[row][c4 * 4 + 1] = v.y;
    tile[row][c4 * 4 + 2] = v.z; tile[row][c4 * 4 + 3] = v.w;
  }
  __syncthreads();
  #pragma unroll
  for (int i = 0; i < 2; ++i) {
    int idx = i * 256 + t;
    int n  = idx >> 3;       // 0..63 (n within tile)
    int k8 = idx & 7;        // 8-element k-chunk
    u16x8 v;
    #pragma unroll
    for (int e = 0; e < 8; ++e) v[e] = f2bf(tile[k8 * 8 + e][n]);
    *reinterpret_cast<u16x8*>(&wt[(size_t)(n0 + n) * K_DIM + k0 + k8 * 8]) = v;
  }
}

// ---------- Pass 2: bf16 MFMA GEMM, m97 128x128x32 structure ----------
// A: [M][K] bf16 row-major; Bt: [N][K] bf16 row-major (both K-contiguous).
__global__ __launch_bounds__(256) void gemm_qkv(const unsigned short* __restrict__ A,
                                                const unsigned short* __restrict__ Bt,
                                                const float* __restrict__ bias,
                                                float* __restrict__ out) {
  __shared__ unsigned short As[128 * 32];   // 8 KB, row stride 32 elem (64B)
  __shared__ unsigned short Bs[128 * 32];   // 8 KB
  const int bid = blockIdx.x;
  const int bm = bid / 48, bn = bid % 48;   // 128 x 48 blocks
  const int m0 = bm * 128, n0 = bn * 128;
  const int tid  = threadIdx.x;
  const int lane = tid & 63;
  const int wid  = tid >> 6;                 // 4 waves, 2x2 -> 64x64 per wave
  const int wm = wid >> 1, wn = wid & 1;

  // Staging map: call j of wave w covers LDS bytes [(w*2+j)*1024, +1024), lane writes +lane*16.
  // flat elem = ((w*2+j)*64 + lane)*8 -> row = (w*2+j)*16 + lane/4, kpack = (lane&3)*8.
  const int srow = wid * 32 + (lane >> 2);
  const int skp  = (lane & 3) * 8;
  const unsigned short* gA0 = A  + (size_t)(m0 + srow) * K_DIM + skp;
  const unsigned short* gA1 = gA0 + (size_t)16 * K_DIM;
  const unsigned short* gB0 = Bt + (size_t)(n0 + srow) * K_DIM + skp;
  const unsigned short* gB1 = gB0 + (size_t)16 * K_DIM;
  unsigned short* lA0 = As + (wid * 2 + 0) * 512;
  unsigned short* lA1 = As + (wid * 2 + 1) * 512;
  unsigned short* lB0 = Bs + (wid * 2 + 0) * 512;
  unsigned short* lB1 = Bs + (wid * 2 + 1) * 512;

  f32x4 acc[4][4] = {};

  // Fragment read offsets (elements): row*(32) + (lane>>4)*8, row = w*64 + mi*16 + (lane&15)
  const int ar = (wm * 64 + (lane & 15)) * 32 + (lane >> 4) * 8;
  const int br = (wn * 64 + (lane & 15)) * 32 + (lane >> 4) * 8;

  for (int kt = 0; kt < K_DIM / 32; ++kt) {
    const int k0 = kt * 32;
    load_lds16(gA0 + k0, lA0);
    load_lds16(gA1 + k0, lA1);
    load_lds16(gB0 + k0, lB0);
    load_lds16(gB1 + k0, lB1);
    __syncthreads();   // drains vmcnt before barrier (compiler-inserted)

    bf16x8 fa[4], fb[4];
    #pragma unroll
    for (int mi = 0; mi < 4; ++mi)
      fa[mi] = *reinterpret_cast<const bf16x8*>(As + ar + mi * 16 * 32);
    #pragma unroll
    for (int ni = 0; ni < 4; ++ni)
      fb[ni] = *reinterpret_cast<const bf16x8*>(Bs + br + ni * 16 * 32);
    #pragma unroll
    for (int mi = 0; mi < 4; ++mi)
      #pragma unroll
      for (int ni = 0; ni < 4; ++ni)
        acc[mi][ni] = __builtin_amdgcn_mfma_f32_16x16x32_bf16(fa[mi], fb[ni], acc[mi][ni], 0, 0, 0);
    __syncthreads();   // protect LDS before next stage
  }

  // Epilogue: bias + head-split scatter.
  // out = concat(q,k,v), each [4][16][4096][128]. col selects which/head/hd; row selects b/t.
  const int which = n0 >> 11;           // /2048
  const int head  = (n0 & 2047) >> 7;   // /128
  const int bb = m0 >> 12;              // /4096
  const int t0 = m0 & 4095;
  float* ob = out + (size_t)which * 33554432 + (size_t)bb * 8388608 + (size_t)head * 524288;
  #pragma unroll
  for (int ni = 0; ni < 4; ++ni) {
    const int col = wn * 64 + ni * 16 + (lane & 15);
    const float bv = bias[n0 + col];
    #pragma unroll
    for (int mi = 0; mi < 4; ++mi) {
      #pragma unroll
      for (int r = 0; r < 4; ++r) {
        const int ml = wm * 64 + mi * 16 + (lane >> 4) * 4 + r;
        ob[(size_t)(t0 + ml) * 128 + col] = acc[mi][ni][r] + bv;
      }
    }
  }
}

// ---------- Fallback (ws too small): naive fp32, correct but slow ----------
__global__ __launch_bounds__(256) void naive_qkv(const float* __restrict__ h,
                                                 const float* __restrict__ w,
                                                 const float* __restrict__ bias,
                                                 float* __restrict__ out) {
  const int m = blockIdx.x;
  const int n = blockIdx.y * 256 + threadIdx.x;
  const float* hr = h + (size_t)m * K_DIM;
  float acc = bias[n];
  for (int k = 0; k < K_DIM; ++k) acc = fmaf(hr[k], w[(size_t)k * N_DIM + n], acc);
  const int which = n >> 11, head = (n & 2047) >> 7, hd = n & 127;
  const int bb = m >> 12, tt = m & 4095;
  out[(size_t)which * 33554432 + (size_t)bb * 8388608 + (size_t)head * 524288 +
      (size_t)tt * 128 + hd] = acc;
}

extern "C" void kernel_launch(void* const* d_in, const int* in_sizes, int n_in,
                              void* d_out, int out_size, void* d_ws, size_t ws_size,
                              hipStream_t stream) {
  const float* hidden = (const float*)d_in[0];
  const float* w_qkv  = (const float*)d_in[1];
  const float* b_qkv  = (const float*)d_in[2];
  float* out = (float*)d_out;

  const size_t needA = (size_t)M_DIM * K_DIM * 2;   // 67,108,864 B
  const size_t needB = (size_t)N_DIM * K_DIM * 2;   // 25,165,824 B
  if (ws_size >= needA + needB) {
    unsigned short* Abf = (unsigned short*)d_ws;
    unsigned short* Wt  = (unsigned short*)((char*)d_ws + needA);
    cvt_hidden<<<2048, 256, 0, stream>>>(hidden, Abf);
    cvt_w<<<dim3(32, 96), 256, 0, stream>>>(w_qkv, Wt);
    gemm_qkv<<<6144, 256, 0, stream>>>(Abf, Wt, b_qkv, out);
  } else {
    naive_qkv<<<dim3(16384, 24), 256, 0, stream>>>(hidden, w_qkv, b_qkv, out);
  }
}

// Round 2
// 498.157 us; speedup vs baseline: 1.1646x; 1.1646x over previous
//
#include <hip/hip_runtime.h>
#include <hip/hip_bf16.h>
#include <stdint.h>

#define M_DIM 16384   // B*T = 4*4096
#define K_DIM 2048    // H
#define N_DIM 6144    // 3H
#define NT    32      // K_DIM / 64 K-tiles

typedef __attribute__((ext_vector_type(8))) short bf16x8;
typedef __attribute__((ext_vector_type(8))) unsigned short u16x8;
typedef __attribute__((ext_vector_type(4))) float f32x4;

__device__ __forceinline__ unsigned short f2bf(float f) {
  unsigned int u = __float_as_uint(f);
  u += 0x7FFFu + ((u >> 16) & 1u);   // RNE
  return (unsigned short)(u >> 16);
}

__device__ __forceinline__ void load_lds16(const void* g, void* l) {
  __builtin_amdgcn_global_load_lds((const __attribute__((address_space(1))) void*)g,
                                   (__attribute__((address_space(3))) void*)l, 16, 0, 0);
}

#define FENCE asm volatile("" ::: "memory")
#define BAR   do { FENCE; __builtin_amdgcn_s_barrier(); FENCE; } while (0)
#define LGKM0 do { asm volatile("s_waitcnt lgkmcnt(0)" ::: "memory"); \
                   __builtin_amdgcn_sched_barrier(0); } while (0)

// ---------- Pass 1a: hidden fp32 -> bf16 ----------
__global__ __launch_bounds__(256) void cvt_hidden(const float* __restrict__ in,
                                                  unsigned short* __restrict__ out) {
  unsigned int base = blockIdx.x * 256u + threadIdx.x;
  #pragma unroll
  for (int i = 0; i < 16; ++i) {
    unsigned int fi = i * 524288u + base;
    float4 v = reinterpret_cast<const float4*>(in)[fi];
    ushort4 o;
    o.x = f2bf(v.x); o.y = f2bf(v.y); o.z = f2bf(v.z); o.w = f2bf(v.w);
    reinterpret_cast<ushort4*>(out)[fi] = o;
  }
}

// ---------- Pass 1b: w_qkv [K][N] fp32 -> Wt [N][K] bf16 ----------
__global__ __launch_bounds__(256) void cvt_w(const float* __restrict__ w,
                                             unsigned short* __restrict__ wt) {
  __shared__ float tile[64][69];
  const int k0 = blockIdx.x * 64;
  const int n0 = blockIdx.y * 64;
  const int t = threadIdx.x;
  #pragma unroll
  for (int i = 0; i < 4; ++i) {
    int idx = i * 256 + t;
    int row = idx >> 4, c4 = idx & 15;
    float4 v = *reinterpret_cast<const float4*>(&w[(size_t)(k0 + row) * N_DIM + n0 + c4 * 4]);
    tile[row][c4 * 4 + 0] = v.x; tile[row][c4 * 4 + 1] = v.y;
    tile[row][c4 * 4 + 2] = v.z; tile[row][c4 * 4 + 3] = v.w;
  }
  __syncthreads();
  #pragma unroll
  for (int i = 0; i < 2; ++i) {
    int idx = i * 256 + t;
    int n = idx >> 3, k8 = idx & 7;
    u16x8 v;
    #pragma unroll
    for (int e = 0; e < 8; ++e) v[e] = f2bf(tile[k8 * 8 + e][n]);
    *reinterpret_cast<u16x8*>(&wt[(size_t)(n0 + n) * K_DIM + k0 + k8 * 8]) = v;
  }
}

// ---------- Pass 2: 256x256x64 8-phase bf16 MFMA GEMM (m201 template) ----------
// A [M][K] bf16, Bt [N][K] bf16 (both K-contiguous).
// LDS (dynamic 128 KiB): buf{0,1} x { A: 256 rows x 128B, B: 256 rows x 128B }.
// Swizzle: LDS(row, slot16B) holds global k-slot (slot ^ (row&7)).
//   write side: global_load_lds linear dest + pre-swizzled global source col
//   read side:  ds_read at slot (logical ^ (row&7)); row&7 == lane&7 for frags.
// Pipeline: iter t computes K-tile t from buf[t&1]; stages K-tile t+2 into the
//   SAME buffer, B-region in ph3 (B reads complete at ph2's lgkmcnt+barrier),
//   A-region in ph4 (A reads complete at ph3). vmcnt(8) at ph4 leaves K(t+2)'s
//   8 loads in flight; barrier after it guarantees K(t+1) fully landed for all
//   waves before next iter reads it.
__global__ __launch_bounds__(512, 2) void gemm_qkv_8ph(const unsigned short* __restrict__ A,
                                                       const unsigned short* __restrict__ Bt,
                                                       const float* __restrict__ bias,
                                                       float* __restrict__ out) {
  extern __shared__ __align__(16) char smem[];
  const int tid = threadIdx.x, lane = tid & 63, wid = tid >> 6;
  const int wm = wid >> 2, wn = wid & 3;        // 2 x 4 wave grid, 128x64 per wave

  // XCD-aware swizzle (nwg=1536, 1536%8==0 -> simple form is bijective)
  const int bid = blockIdx.x;
  const int swz = (bid & 7) * 192 + (bid >> 3);
  const int bm = swz / 24, bn = swz % 24;
  const int m0 = bm * 256, n0 = bn * 256;

  // ---- staging addresses (constant per thread) ----
  const int srow  = tid >> 3;                          // 0..63
  const int sslot = (tid & 7) ^ ((tid >> 3) & 7);      // pre-swizzled source slot
  const unsigned short* gA = A  + (size_t)(m0 + srow) * K_DIM + sslot * 8;
  const unsigned short* gB = Bt + (size_t)(n0 + srow) * K_DIM + sslot * 8;

  // ---- fragment read offsets ----
  const int r15 = lane & 15, q4 = lane >> 4, x7 = lane & 7;
  const int abase = (wm * 128 + r15) * 128;            // byte offset in A tile
  const int bbase = (wn * 64  + r15) * 128;            // byte offset in B tile
  const int sw0 = ((0 + q4) ^ x7) * 16;                // ksub 0 swizzled slot
  const int sw1 = ((4 + q4) ^ x7) * 16;                // ksub 1 swizzled slot

  f32x4 acc[2][2][4][2] = {};                          // [qm][qn][mi][ni]
  bf16x8 a[4][2], b0[2][2], b1[2][2];

  // stage one full 256x64 tile (32 KB): 4 x global_load_lds(16B) per thread
  #define STAGE_T(gsrc, ldsbase)                                              \
    { const unsigned short* _g = (gsrc); char* _l = (ldsbase);                \
      load_lds16(_g,                       _l +     wid * 1024);              \
      load_lds16(_g + (size_t)64  * K_DIM, _l + 8192  + wid * 1024);          \
      load_lds16(_g + (size_t)128 * K_DIM, _l + 16384 + wid * 1024);          \
      load_lds16(_g + (size_t)192 * K_DIM, _l + 24576 + wid * 1024); }

  // ---- prologue: K0.B, K0.A, K1.B, K1.A (16 loads), wait oldest 8 ----
  {
    char* A0 = smem;          char* B0 = smem + 32768;
    char* A1 = smem + 65536;  char* B1 = smem + 98304;
    STAGE_T(gB +  0, B0); STAGE_T(gA +  0, A0);
    STAGE_T(gB + 64, B1); STAGE_T(gA + 64, A1);
    asm volatile("s_waitcnt vmcnt(8)" ::: "memory");   // K0 landed (per wave)
    BAR;                                               // -> landed for ALL waves
  }

  for (int t = 0; t < NT; ++t) {
    char* Ab = smem + (t & 1) * 65536;
    char* Bb = Ab + 32768;
    const bool st = (t + 2 < NT);

    // ---- ph1: read A(qm0) + B(qn0); MFMA quad(0,0) ----
    #pragma unroll
    for (int mi = 0; mi < 4; ++mi) {
      const char* p = Ab + abase + mi * (16 * 128);
      a[mi][0] = *(const bf16x8*)(p + sw0);
      a[mi][1] = *(const bf16x8*)(p + sw1);
    }
    #pragma unroll
    for (int ni = 0; ni < 2; ++ni) {
      const char* p = Bb + bbase + ni * (16 * 128);
      b0[ni][0] = *(const bf16x8*)(p + sw0);
      b0[ni][1] = *(const bf16x8*)(p + sw1);
    }
    BAR; LGKM0;
    __builtin_amdgcn_s_setprio(1);
    #pragma unroll
    for (int mi = 0; mi < 4; ++mi)
      #pragma unroll
      for (int ni = 0; ni < 2; ++ni) {
        acc[0][0][mi][ni] = __builtin_amdgcn_mfma_f32_16x16x32_bf16(a[mi][0], b0[ni][0], acc[0][0][mi][ni], 0, 0, 0);
        acc[0][0][mi][ni] = __builtin_amdgcn_mfma_f32_16x16x32_bf16(a[mi][1], b0[ni][1], acc[0][0][mi][ni], 0, 0, 0);
      }
    __builtin_amdgcn_s_setprio(0);
    BAR;

    // ---- ph2: read B(qn1); MFMA quad(0,1) ----
    #pragma unroll
    for (int ni = 0; ni < 2; ++ni) {
      const char* p = Bb + bbase + (32 + ni * 16) * 128;
      b1[ni][0] = *(const bf16x8*)(p + sw0);
      b1[ni][1] = *(const bf16x8*)(p + sw1);
    }
    BAR; LGKM0;
    __builtin_amdgcn_s_setprio(1);
    #pragma unroll
    for (int mi = 0; mi < 4; ++mi)
      #pragma unroll
      for (int ni = 0; ni < 2; ++ni) {
        acc[0][1][mi][ni] = __builtin_amdgcn_mfma_f32_16x16x32_bf16(a[mi][0], b1[ni][0], acc[0][1][mi][ni], 0, 0, 0);
        acc[0][1][mi][ni] = __builtin_amdgcn_mfma_f32_16x16x32_bf16(a[mi][1], b1[ni][1], acc[0][1][mi][ni], 0, 0, 0);
      }
    __builtin_amdgcn_s_setprio(0);
    BAR;

    // ---- ph3: read A(qm1); stage K(t+2).B (B region free after ph2 BAR);
    //           MFMA quad(1,0) ----
    #pragma unroll
    for (int mi = 0; mi < 4; ++mi) {
      const char* p = Ab + abase + (64 + mi * 16) * 128;
      a[mi][0] = *(const bf16x8*)(p + sw0);
      a[mi][1] = *(const bf16x8*)(p + sw1);
    }
    if (st) STAGE_T(gB + (size_t)(t + 2) * 64, Bb);
    BAR; LGKM0;
    __builtin_amdgcn_s_setprio(1);
    #pragma unroll
    for (int mi = 0; mi < 4; ++mi)
      #pragma unroll
      for (int ni = 0; ni < 2; ++ni) {
        acc[1][0][mi][ni] = __builtin_amdgcn_mfma_f32_16x16x32_bf16(a[mi][0], b0[ni][0], acc[1][0][mi][ni], 0, 0, 0);
        acc[1][0][mi][ni] = __builtin_amdgcn_mfma_f32_16x16x32_bf16(a[mi][1], b0[ni][1], acc[1][0][mi][ni], 0, 0, 0);
      }
    __builtin_amdgcn_s_setprio(0);
    BAR;

    // ---- ph4: stage K(t+2).A (A region free after ph3 BAR); MFMA quad(1,1);
    //           counted vmcnt; barrier opens next K-tile ----
    if (st) STAGE_T(gA + (size_t)(t + 2) * 64, Ab);
    BAR; LGKM0;
    __builtin_amdgcn_s_setprio(1);
    #pragma unroll
    for (int mi = 0; mi < 4; ++mi)
      #pragma unroll
      for (int ni = 0; ni < 2; ++ni) {
        acc[1][1][mi][ni] = __builtin_amdgcn_mfma_f32_16x16x32_bf16(a[mi][0], b1[ni][0], acc[1][1][mi][ni], 0, 0, 0);
        acc[1][1][mi][ni] = __builtin_amdgcn_mfma_f32_16x16x32_bf16(a[mi][1], b1[ni][1], acc[1][1][mi][ni], 0, 0, 0);
      }
    __builtin_amdgcn_s_setprio(0);
    if (st) { asm volatile("s_waitcnt vmcnt(8)" ::: "memory"); }  // K(t+1) done, K(t+2) in flight
    else    { asm volatile("s_waitcnt vmcnt(0)" ::: "memory"); }  // tail drain
    BAR;
  }
  #undef STAGE_T

  // ---- epilogue: bias + q/k/v head scatter ----
  // out = [3][4][16][4096][128]; C/D frag: col=lane&15 (n), row=(lane>>4)*4+r (m)
  #pragma unroll
  for (int qn = 0; qn < 2; ++qn)
    #pragma unroll
    for (int ni = 0; ni < 2; ++ni) {
      const int col = n0 + wn * 64 + qn * 32 + ni * 16 + r15;
      const float bv = bias[col];
      const int which = col >> 11, head = (col & 2047) >> 7, hd = col & 127;
      float* ob = out + (size_t)which * 33554432 + (size_t)head * 524288 + hd;
      #pragma unroll
      for (int qm = 0; qm < 2; ++qm)
        #pragma unroll
        for (int mi = 0; mi < 4; ++mi)
          #pragma unroll
          for (int r = 0; r < 4; ++r) {
            const int mrow = m0 + wm * 128 + qm * 64 + mi * 16 + q4 * 4 + r;
            const int bb_ = mrow >> 12, tt = mrow & 4095;
            ob[(size_t)bb_ * 8388608 + (size_t)tt * 128] = acc[qm][qn][mi][ni][r] + bv;
          }
    }
}

// ---------- Fallback: naive fp32 ----------
__global__ __launch_bounds__(256) void naive_qkv(const float* __restrict__ h,
                                                 const float* __restrict__ w,
                                                 const float* __restrict__ bias,
                                                 float* __restrict__ out) {
  const int m = blockIdx.x;
  const int n = blockIdx.y * 256 + threadIdx.x;
  const float* hr = h + (size_t)m * K_DIM;
  float acc = bias[n];
  for (int k = 0; k < K_DIM; ++k) acc = fmaf(hr[k], w[(size_t)k * N_DIM + n], acc);
  const int which = n >> 11, head = (n & 2047) >> 7, hd = n & 127;
  const int bb = m >> 12, tt = m & 4095;
  out[(size_t)which * 33554432 + (size_t)bb * 8388608 + (size_t)head * 524288 +
      (size_t)tt * 128 + hd] = acc;
}

extern "C" void kernel_launch(void* const* d_in, const int* in_sizes, int n_in,
                              void* d_out, int out_size, void* d_ws, size_t ws_size,
                              hipStream_t stream) {
  const float* hidden = (const float*)d_in[0];
  const float* w_qkv  = (const float*)d_in[1];
  const float* b_qkv  = (const float*)d_in[2];
  float* out = (float*)d_out;

  const size_t needA = (size_t)M_DIM * K_DIM * 2;
  const size_t needB = (size_t)N_DIM * K_DIM * 2;
  if (ws_size >= needA + needB) {
    unsigned short* Abf = (unsigned short*)d_ws;
    unsigned short* Wt  = (unsigned short*)((char*)d_ws + needA);
    (void)hipFuncSetAttribute((const void*)gemm_qkv_8ph,
                              hipFuncAttributeMaxDynamicSharedMemorySize, 131072);
    cvt_hidden<<<2048, 256, 0, stream>>>(hidden, Abf);
    cvt_w<<<dim3(32, 96), 256, 0, stream>>>(w_qkv, Wt);
    gemm_qkv_8ph<<<1536, 512, 131072, stream>>>(Abf, Wt, b_qkv, out);
  } else {
    naive_qkv<<<dim3(16384, 24), 256, 0, stream>>>(hidden, w_qkv, b_qkv, out);
  }
}

// Round 3
// 479.729 us; speedup vs baseline: 1.2093x; 1.0384x over previous
//
#include <hip/hip_runtime.h>
#include <hip/hip_bf16.h>
#include <stdint.h>

#define M_DIM 16384   // B*T = 4*4096
#define K_DIM 2048    // H
#define N_DIM 6144    // 3H
#define NT    32      // K-tiles per output tile (K_DIM/64)
#define NTILES 6      // output tiles per persistent block (1536/256)

typedef __attribute__((ext_vector_type(8))) short bf16x8;
typedef __attribute__((ext_vector_type(8))) unsigned short u16x8;
typedef __attribute__((ext_vector_type(4))) float f32x4;

__device__ __forceinline__ unsigned short f2bf(float f) {
  unsigned int u = __float_as_uint(f);
  u += 0x7FFFu + ((u >> 16) & 1u);   // RNE
  return (unsigned short)(u >> 16);
}

__device__ __forceinline__ void load_lds16(const void* g, void* l) {
  __builtin_amdgcn_global_load_lds((const __attribute__((address_space(1))) void*)g,
                                   (__attribute__((address_space(3))) void*)l, 16, 0, 0);
}

#define FENCE asm volatile("" ::: "memory")
#define BAR   do { FENCE; __builtin_amdgcn_s_barrier(); FENCE; } while (0)
#define LGKM0 do { asm volatile("s_waitcnt lgkmcnt(0)" ::: "memory"); \
                   __builtin_amdgcn_sched_barrier(0); } while (0)

// ---------- Pass 1a: hidden fp32 -> bf16 ----------
__global__ __launch_bounds__(256) void cvt_hidden(const float* __restrict__ in,
                                                  unsigned short* __restrict__ out) {
  unsigned int base = blockIdx.x * 256u + threadIdx.x;
  #pragma unroll
  for (int i = 0; i < 16; ++i) {
    unsigned int fi = i * 524288u + base;
    float4 v = reinterpret_cast<const float4*>(in)[fi];
    ushort4 o;
    o.x = f2bf(v.x); o.y = f2bf(v.y); o.z = f2bf(v.z); o.w = f2bf(v.w);
    reinterpret_cast<ushort4*>(out)[fi] = o;
  }
}

// ---------- Pass 1b: w_qkv [K][N] fp32 -> Wt [N][K] bf16 ----------
__global__ __launch_bounds__(256) void cvt_w(const float* __restrict__ w,
                                             unsigned short* __restrict__ wt) {
  __shared__ float tile[64][69];
  const int k0 = blockIdx.x * 64;
  const int n0 = blockIdx.y * 64;
  const int t = threadIdx.x;
  #pragma unroll
  for (int i = 0; i < 4; ++i) {
    int idx = i * 256 + t;
    int row = idx >> 4, c4 = idx & 15;
    float4 v = *reinterpret_cast<const float4*>(&w[(size_t)(k0 + row) * N_DIM + n0 + c4 * 4]);
    tile[row][c4 * 4 + 0] = v.x; tile[row][c4 * 4 + 1] = v.y;
    tile[row][c4 * 4 + 2] = v.z; tile[row][c4 * 4 + 3] = v.w;
  }
  __syncthreads();
  #pragma unroll
  for (int i = 0; i < 2; ++i) {
    int idx = i * 256 + t;
    int n = idx >> 3, k8 = idx & 7;
    u16x8 v;
    #pragma unroll
    for (int e = 0; e < 8; ++e) v[e] = f2bf(tile[k8 * 8 + e][n]);
    *reinterpret_cast<u16x8*>(&wt[(size_t)(n0 + n) * K_DIM + k0 + k8 * 8]) = v;
  }
}

// ---------- Pass 2: persistent 256x256x64 8-phase bf16 MFMA GEMM ----------
// A [M][K] bf16, Bt [N][K] bf16. LDS 128 KiB: buf{0,1} x {A 32KB, B 32KB}.
// Swizzle st-style: LDS(row, slot16B) holds k-slot (slot ^ (row&7));
//   linear gload_lds dest + pre-swizzled global source + swizzled ds_read.
// Per tile: iter t computes K-tile t from buf[t&1]; stages K(t+2).B in ph3,
//   K(t+2).A in ph4; vmcnt(8) at ph4 (K(t+1) landed, K(t+2) in flight).
// Cross-tile: after final BAR of tile j, issue tile j+1's K0/K1 loads (16),
//   then 32 float4 epilogue stores, then vmcnt(40): 48 outstanding - 8 oldest
//   => K0 landed; stores + K1 drain under tile j+1's first K-iters.
// MFMA operands SWAPPED (fb, fa): D col(lane&15)=m, row(q4*4+r)=n -> each
//   lane's 4 acc regs are 4 consecutive n-cols => float4 stores.
__global__ __launch_bounds__(512, 2) void gemm_qkv_8ph(const unsigned short* __restrict__ A,
                                                       const unsigned short* __restrict__ Bt,
                                                       const float* __restrict__ bias,
                                                       float* __restrict__ out) {
  extern __shared__ __align__(16) char smem[];
  const int tid = threadIdx.x, lane = tid & 63, wid = tid >> 6;
  const int wm = wid >> 2, wn = wid & 3;        // 2 x 4 wave grid, 128x64 per wave

  const int xcd = blockIdx.x & 7;               // XCD-chunked tile ownership
  const int lcl = blockIdx.x >> 3;              // 0..31 within XCD

  const int srow  = tid >> 3;
  const int sslot = (tid & 7) ^ ((tid >> 3) & 7);
  const int r15 = lane & 15, q4 = lane >> 4, x7 = lane & 7;
  const int abase = (wm * 128 + r15) * 128;
  const int bbase = (wn * 64  + r15) * 128;
  const int sw0 = ((0 + q4) ^ x7) * 16;
  const int sw1 = ((4 + q4) ^ x7) * 16;

  // stage one full 256x64 tile (32 KB): 4 x gload_lds(16B) per thread
  #define STAGE_T(gsrc, ldsbase)                                              \
    { const unsigned short* _g = (gsrc); char* _l = (ldsbase);                \
      load_lds16(_g,                       _l +     wid * 1024);              \
      load_lds16(_g + (size_t)64  * K_DIM, _l + 8192  + wid * 1024);          \
      load_lds16(_g + (size_t)128 * K_DIM, _l + 16384 + wid * 1024);          \
      load_lds16(_g + (size_t)192 * K_DIM, _l + 24576 + wid * 1024); }

  // tile j (0..5): idx = j*32 + lcl; concurrent blocks span ~1.3 bm-rows/XCD
  #define TILE_PARAMS(j, m0_, n0_, gA_, gB_)                                  \
    { const int idx = (j) * 32 + lcl;                                         \
      const int bm = xcd * 8 + idx / 24, bn = idx % 24;                       \
      m0_ = bm * 256; n0_ = bn * 256;                                         \
      gA_ = A  + (size_t)(m0_ + srow) * K_DIM + sslot * 8;                    \
      gB_ = Bt + (size_t)(n0_ + srow) * K_DIM + sslot * 8; }

  char* A0 = smem;          char* B0 = smem + 32768;
  char* A1 = smem + 65536;  char* B1 = smem + 98304;

  int m0, n0;
  const unsigned short *gA, *gB;
  TILE_PARAMS(0, m0, n0, gA, gB);
  STAGE_T(gB +  0, B0); STAGE_T(gA +  0, A0);
  STAGE_T(gB + 64, B1); STAGE_T(gA + 64, A1);
  asm volatile("s_waitcnt vmcnt(8)" ::: "memory");   // K0 landed
  BAR;

  for (int j = 0; j < NTILES; ++j) {
    // bias for this tile: float4 per (qn,ni)
    float4 bv4[2][2];
    #pragma unroll
    for (int qn = 0; qn < 2; ++qn)
      #pragma unroll
      for (int ni = 0; ni < 2; ++ni)
        bv4[qn][ni] = *reinterpret_cast<const float4*>(
            &bias[n0 + wn * 64 + qn * 32 + ni * 16 + q4 * 4]);

    f32x4 acc[2][2][4][2] = {};                      // [qm][qn][mi][ni]
    bf16x8 a[4][2], b0[2][2], b1[2][2];

    for (int t = 0; t < NT; ++t) {
      char* Ab = smem + (t & 1) * 65536;
      char* Bb = Ab + 32768;
      const bool st = (t + 2 < NT);

      // ---- ph1: read A(qm0)+B(qn0); MFMA quad(0,0) ----
      #pragma unroll
      for (int mi = 0; mi < 4; ++mi) {
        const char* p = Ab + abase + mi * (16 * 128);
        a[mi][0] = *(const bf16x8*)(p + sw0);
        a[mi][1] = *(const bf16x8*)(p + sw1);
      }
      #pragma unroll
      for (int ni = 0; ni < 2; ++ni) {
        const char* p = Bb + bbase + ni * (16 * 128);
        b0[ni][0] = *(const bf16x8*)(p + sw0);
        b0[ni][1] = *(const bf16x8*)(p + sw1);
      }
      BAR; LGKM0;
      __builtin_amdgcn_s_setprio(1);
      #pragma unroll
      for (int mi = 0; mi < 4; ++mi)
        #pragma unroll
        for (int ni = 0; ni < 2; ++ni) {
          acc[0][0][mi][ni] = __builtin_amdgcn_mfma_f32_16x16x32_bf16(b0[ni][0], a[mi][0], acc[0][0][mi][ni], 0, 0, 0);
          acc[0][0][mi][ni] = __builtin_amdgcn_mfma_f32_16x16x32_bf16(b0[ni][1], a[mi][1], acc[0][0][mi][ni], 0, 0, 0);
        }
      __builtin_amdgcn_s_setprio(0);
      BAR;

      // ---- ph2: read B(qn1); MFMA quad(0,1) ----
      #pragma unroll
      for (int ni = 0; ni < 2; ++ni) {
        const char* p = Bb + bbase + (32 + ni * 16) * 128;
        b1[ni][0] = *(const bf16x8*)(p + sw0);
        b1[ni][1] = *(const bf16x8*)(p + sw1);
      }
      BAR; LGKM0;
      __builtin_amdgcn_s_setprio(1);
      #pragma unroll
      for (int mi = 0; mi < 4; ++mi)
        #pragma unroll
        for (int ni = 0; ni < 2; ++ni) {
          acc[0][1][mi][ni] = __builtin_amdgcn_mfma_f32_16x16x32_bf16(b1[ni][0], a[mi][0], acc[0][1][mi][ni], 0, 0, 0);
          acc[0][1][mi][ni] = __builtin_amdgcn_mfma_f32_16x16x32_bf16(b1[ni][1], a[mi][1], acc[0][1][mi][ni], 0, 0, 0);
        }
      __builtin_amdgcn_s_setprio(0);
      BAR;

      // ---- ph3: read A(qm1); stage K(t+2).B; MFMA quad(1,0) ----
      #pragma unroll
      for (int mi = 0; mi < 4; ++mi) {
        const char* p = Ab + abase + (64 + mi * 16) * 128;
        a[mi][0] = *(const bf16x8*)(p + sw0);
        a[mi][1] = *(const bf16x8*)(p + sw1);
      }
      if (st) STAGE_T(gB + (size_t)(t + 2) * 64, Bb);
      BAR; LGKM0;
      __builtin_amdgcn_s_setprio(1);
      #pragma unroll
      for (int mi = 0; mi < 4; ++mi)
        #pragma unroll
        for (int ni = 0; ni < 2; ++ni) {
          acc[1][0][mi][ni] = __builtin_amdgcn_mfma_f32_16x16x32_bf16(b0[ni][0], a[mi][0], acc[1][0][mi][ni], 0, 0, 0);
          acc[1][0][mi][ni] = __builtin_amdgcn_mfma_f32_16x16x32_bf16(b0[ni][1], a[mi][1], acc[1][0][mi][ni], 0, 0, 0);
        }
      __builtin_amdgcn_s_setprio(0);
      BAR;

      // ---- ph4: stage K(t+2).A; MFMA quad(1,1); counted vmcnt ----
      if (st) STAGE_T(gA + (size_t)(t + 2) * 64, Ab);
      BAR; LGKM0;
      __builtin_amdgcn_s_setprio(1);
      #pragma unroll
      for (int mi = 0; mi < 4; ++mi)
        #pragma unroll
        for (int ni = 0; ni < 2; ++ni) {
          acc[1][1][mi][ni] = __builtin_amdgcn_mfma_f32_16x16x32_bf16(b1[ni][0], a[mi][0], acc[1][1][mi][ni], 0, 0, 0);
          acc[1][1][mi][ni] = __builtin_amdgcn_mfma_f32_16x16x32_bf16(b1[ni][1], a[mi][1], acc[1][1][mi][ni], 0, 0, 0);
        }
      __builtin_amdgcn_s_setprio(0);
      if (st) { asm volatile("s_waitcnt vmcnt(8)" ::: "memory"); }  // K(t+1) done
      else    { asm volatile("s_waitcnt vmcnt(0)" ::: "memory"); }  // tail drain
      BAR;
    }

    // ---- cross-tile: issue next tile's prologue loads FIRST ----
    const int cm0 = m0, cn0 = n0;
    if (j + 1 < NTILES) {
      TILE_PARAMS(j + 1, m0, n0, gA, gB);
      STAGE_T(gB +  0, B0); STAGE_T(gA +  0, A0);
      STAGE_T(gB + 64, B1); STAGE_T(gA + 64, A1);
    }

    // ---- epilogue: 32 float4 stores (bias pre-added) ----
    // m = cm0 + wm*128 + qm*64 + mi*16 + r15 ; n = cn0 + wn*64 + qn*32 + ni*16 + q4*4 + r
    #pragma unroll
    for (int qm = 0; qm < 2; ++qm)
      #pragma unroll
      for (int mi = 0; mi < 4; ++mi) {
        const int m = cm0 + wm * 128 + qm * 64 + mi * 16 + r15;
        const int bb_ = m >> 12, tt = m & 4095;
        float* orow = out + (size_t)bb_ * 8388608 + (size_t)tt * 128;
        #pragma unroll
        for (int qn = 0; qn < 2; ++qn)
          #pragma unroll
          for (int ni = 0; ni < 2; ++ni) {
            const int col = cn0 + wn * 64 + qn * 32 + ni * 16 + q4 * 4;
            const int which = col >> 11, head = (col & 2047) >> 7, hd = col & 127;
            float4 v;
            v.x = acc[qm][qn][mi][ni][0] + bv4[qn][ni].x;
            v.y = acc[qm][qn][mi][ni][1] + bv4[qn][ni].y;
            v.z = acc[qm][qn][mi][ni][2] + bv4[qn][ni].z;
            v.w = acc[qm][qn][mi][ni][3] + bv4[qn][ni].w;
            *reinterpret_cast<float4*>(orow + (size_t)which * 33554432 +
                                       (size_t)head * 524288 + hd) = v;
          }
      }

    if (j + 1 < NTILES) {
      // 16 loads + 32 stores outstanding; 8 oldest done => next K0 landed.
      asm volatile("s_waitcnt vmcnt(40)" ::: "memory");
      BAR;
    }
  }
  #undef STAGE_T
  #undef TILE_PARAMS
}

// ---------- Fallback: naive fp32 ----------
__global__ __launch_bounds__(256) void naive_qkv(const float* __restrict__ h,
                                                 const float* __restrict__ w,
                                                 const float* __restrict__ bias,
                                                 float* __restrict__ out) {
  const int m = blockIdx.x;
  const int n = blockIdx.y * 256 + threadIdx.x;
  const float* hr = h + (size_t)m * K_DIM;
  float acc = bias[n];
  for (int k = 0; k < K_DIM; ++k) acc = fmaf(hr[k], w[(size_t)k * N_DIM + n], acc);
  const int which = n >> 11, head = (n & 2047) >> 7, hd = n & 127;
  const int bb = m >> 12, tt = m & 4095;
  out[(size_t)which * 33554432 + (size_t)bb * 8388608 + (size_t)head * 524288 +
      (size_t)tt * 128 + hd] = acc;
}

extern "C" void kernel_launch(void* const* d_in, const int* in_sizes, int n_in,
                              void* d_out, int out_size, void* d_ws, size_t ws_size,
                              hipStream_t stream) {
  const float* hidden = (const float*)d_in[0];
  const float* w_qkv  = (const float*)d_in[1];
  const float* b_qkv  = (const float*)d_in[2];
  float* out = (float*)d_out;

  const size_t needA = (size_t)M_DIM * K_DIM * 2;
  const size_t needB = (size_t)N_DIM * K_DIM * 2;
  if (ws_size >= needA + needB) {
    unsigned short* Abf = (unsigned short*)d_ws;
    unsigned short* Wt  = (unsigned short*)((char*)d_ws + needA);
    (void)hipFuncSetAttribute((const void*)gemm_qkv_8ph,
                              hipFuncAttributeMaxDynamicSharedMemorySize, 131072);
    cvt_hidden<<<2048, 256, 0, stream>>>(hidden, Abf);
    cvt_w<<<dim3(32, 96), 256, 0, stream>>>(w_qkv, Wt);
    gemm_qkv_8ph<<<256, 512, 131072, stream>>>(Abf, Wt, b_qkv, out);
  } else {
    naive_qkv<<<dim3(16384, 24), 256, 0, stream>>>(hidden, w_qkv, b_qkv, out);
  }
}